// Round 1
// baseline (106.629 us; speedup 1.0000x reference)
//
#include <hip/hip_runtime.h>
#include <hip/hip_bf16.h>
#include <stdint.h>

typedef __attribute__((ext_vector_type(8))) short bf16x8;
typedef __attribute__((ext_vector_type(4))) float f32x4;
typedef __attribute__((ext_vector_type(16))) float f32x16;

#define MFMA16(a,b,c) __builtin_amdgcn_mfma_f32_16x16x32_bf16((a),(b),(c),0,0,0)
#define MFMA32(a,b,c) __builtin_amdgcn_mfma_f32_32x32x16_bf16((a),(b),(c),0,0,0)
#define AS1 __attribute__((address_space(1)))
#define AS3 __attribute__((address_space(3)))

__device__ inline short f2bf(float f) {
    union { __hip_bfloat16 h; short s; } u;
    u.h = __float2bfloat16(f);
    return u.s;
}
__device__ inline uint32_t pack_bf16(float a, float b) {
    union { __hip_bfloat16 h; uint16_t u; } ua, ub;
    ua.h = __float2bfloat16(a); ub.h = __float2bfloat16(b);
    return (uint32_t)ua.u | ((uint32_t)ub.u << 16);
}

// cross-half register exchange
#if __has_builtin(__builtin_amdgcn_permlane32_swap)
#define SWAP32(x, y, a, b) { auto _r = __builtin_amdgcn_permlane32_swap((a),(b),false,false); \
                             (x) = _r[0]; (y) = _r[1]; }
#else
#define SWAP32(x, y, a, b) { uint32_t _ta = __shfl_xor((uint32_t)(a),32); \
                             uint32_t _tb = __shfl_xor((uint32_t)(b),32); \
                             (x) = hh_ ? _tb : (a); (y) = hh_ ? (b) : _ta; }
#endif

// S' = S * scale * log2(e): fold into Wq so attention exp is native exp2.
#define QSCALE 0.12751879523879295f   // (1/sqrt(128)) * log2(e)

// ---------------------------------------------------------------------------
// Kernel 1: eff-weight mix -> bf16 W [3][8][128][512]; x f32 -> bf16
// ---------------------------------------------------------------------------
#define NW (8*128*512)        // 524288 per projection
#define NX4 (8192*512/4)      // 1048576 float4 chunks of x

__global__ void prep_kernel(const float* __restrict__ x,
                            const float* __restrict__ w,
                            const float* __restrict__ bK,
                            const float* __restrict__ bQ,
                            const float* __restrict__ bV,
                            short* __restrict__ xb,    // [8192][512]
                            short* __restrict__ W)     // [3][1024][512]  (K,Q,V)
{
    const float w0 = w[0], w1 = w[1], w2 = w[2], w3 = w[3];
    for (int i = blockIdx.x * blockDim.x + threadIdx.x; i < NW + NX4;
         i += gridDim.x * blockDim.x) {
        if (i < NW) {
            int e = i & 511;
            int d = (i >> 9) & 127;
            int h = i >> 16;
            float eff = 0.f;
            if (h < 4) { eff += w2; if (d < 64 && e < 256) eff += w0; }
            if (d < 32 && e < 256) eff += w1;
            if (d < 64) eff += w3;
            W[i]          = f2bf(eff * bK[i]);
            W[i + NW]     = f2bf(eff * bQ[i] * QSCALE);
            W[i + 2*NW]   = f2bf(eff * bV[i]);
        } else {
            int j = i - NW;
            float4 v = ((const float4*)x)[j];
            short4 o;
            o.x = f2bf(v.x); o.y = f2bf(v.y); o.z = f2bf(v.z); o.w = f2bf(v.w);
            ((short4*)xb)[j] = o;
        }
    }
}

// ---------------------------------------------------------------------------
// Kernel 2: C[8192,3072] = xb[8192,512] @ W[3072,512]^T
// K,Q stored [bh][t][d]; V stored TRANSPOSED as pair-rows (matches attn LDS).
// LDS-repacked coalesced epilogue; bijective XCD grid swizzle.
// V global layout: [bh][64 pair-rows][2048 t-pairs...]: pair-row r stores
// d=2r at t-major 2048 shorts, then d=2r+1 (i.e. plain [bh][d][t] -- kept).
// ---------------------------------------------------------------------------
__global__ __launch_bounds__(256)
void proj_gemm(const short* __restrict__ A,    // [8192][512]
               const short* __restrict__ Bw,   // [3072][512]
               short* __restrict__ qkv)
{
    __shared__ short S[128 * 128];             // 32 KB: staging + repack
    short* As = S;                             // 16 KB
    short* Bs = S + 128 * 64;                  // 16 KB
    const int tid = threadIdx.x;
    const int lane = tid & 63;
    const int wave = tid >> 6;
    const int wr = wave >> 1, wc = wave & 1;
    const int l15 = lane & 15, lk = lane >> 4;

    // bijective XCD swizzle: 1536 blocks, 192 consecutive per XCD
    const int wg = (blockIdx.x & 7) * 192 + (blockIdx.x >> 3);
    const int bm = (wg / 24) * 128;
    const int bn = (wg % 24) * 128;

    char* Ab = (char*)As;
    char* Bb = (char*)Bs;
    char* Sb = (char*)S;
    f32x4 acc[4][4] = {};

    for (int k0 = 0; k0 < 512; k0 += 64) {
        __syncthreads();
#pragma unroll
        for (int i = 0; i < 4; ++i) {
            int c = i * 256 + tid;              // 0..1023, 16B chunk
            int lin = c * 16;                   // linear byte in 16 KB tile
            int row = lin >> 7;                 // 0..127
            int cof = ((lin & 127) ^ ((row & 7) << 4)) >> 1;   // shorts
            __builtin_amdgcn_global_load_lds(
                (const AS1 void*)(A + (size_t)(bm + row) * 512 + k0 + cof),
                (AS3 void*)(As + c * 8), 16, 0, 0);
            __builtin_amdgcn_global_load_lds(
                (const AS1 void*)(Bw + (size_t)(bn + row) * 512 + k0 + cof),
                (AS3 void*)(Bs + c * 8), 16, 0, 0);
        }
        __syncthreads();                        // drains vmcnt(0) (m97 pattern)
#pragma unroll
        for (int kk = 0; kk < 2; ++kk) {
            bf16x8 af[4], bfv[4];
#pragma unroll
            for (int mi = 0; mi < 4; ++mi) {
                int row = wr * 64 + mi * 16 + l15;
                af[mi] = *(const bf16x8*)(Ab + ((row * 128 + kk * 64 + lk * 16) ^ ((row & 7) << 4)));
            }
#pragma unroll
            for (int ni = 0; ni < 4; ++ni) {
                int row = wc * 64 + ni * 16 + l15;
                bfv[ni] = *(const bf16x8*)(Bb + ((row * 128 + kk * 64 + lk * 16) ^ ((row & 7) << 4)));
            }
#pragma unroll
            for (int mi = 0; mi < 4; ++mi)
#pragma unroll
                for (int ni = 0; ni < 4; ++ni)
                    acc[mi][ni] = MFMA16(af[mi], bfv[ni], acc[mi][ni]);
        }
    }

    // ---- epilogue: repack C-tile via LDS, store coalesced -----------------
    const int proj = bn >> 10;                  // uniform per block
    const int b = bm >> 11;
    const int bh = b * 8 + ((bn & 1023) >> 7);
    const int tbase = bm & 2047;

    __syncthreads();                            // staging reads done
    if (proj == 2) {
        // V: LDS T[dl][tl] (transpose), pack r-pairs (consecutive tl)
#pragma unroll
        for (int mi = 0; mi < 4; ++mi) {
#pragma unroll
            for (int ni = 0; ni < 4; ++ni) {
                int dl = wc * 64 + ni * 16 + l15;
                int tlb = wr * 64 + mi * 16 + lk * 4;
                int byte0 = (dl * 256 + tlb * 2) ^ ((dl & 7) << 4);
                *(uint32_t*)(Sb + byte0)     = pack_bf16(acc[mi][ni][0], acc[mi][ni][1]);
                *(uint32_t*)(Sb + byte0 + 4) = pack_bf16(acc[mi][ni][2], acc[mi][ni][3]);
            }
        }
    } else {
        // K/Q: LDS T[tl][dl]
#pragma unroll
        for (int mi = 0; mi < 4; ++mi) {
#pragma unroll
            for (int ni = 0; ni < 4; ++ni) {
                int dl = wc * 64 + ni * 16 + l15;
#pragma unroll
                for (int r = 0; r < 4; ++r) {
                    int tl = wr * 64 + mi * 16 + lk * 4 + r;
                    *(short*)(Sb + ((tl * 256 + dl * 2) ^ ((tl & 7) << 4))) = f2bf(acc[mi][ni][r]);
                }
            }
        }
    }
    __syncthreads();

    short* dst;
    if (proj == 2)
        dst = qkv + (size_t)2 * (32 * 2048 * 128) + (size_t)bh * 128 * 2048;
    else
        dst = qkv + (size_t)proj * (32 * 2048 * 128) + (size_t)bh * 2048 * 128;

#pragma unroll
    for (int i = 0; i < 8; ++i) {
        int c = i * 256 + tid;                  // 0..2047 16B chunks
        int row = c >> 4;
        uint4 v = *(const uint4*)(Sb + row * 256 + (((c & 15) * 16) ^ ((row & 7) << 4)));
        if (proj == 2) {
            // row = d, cols = t
            *(uint4*)(dst + (size_t)row * 2048 + tbase + (c & 15) * 8) = v;
        } else {
            // row = t, cols = d
            *(uint4*)(dst + (size_t)(tbase + row) * 128 + (c & 15) * 8) = v;
        }
    }
}

// ---------------------------------------------------------------------------
// Kernel 3: causal flash attention — occupancy-rebalanced structure.
// Old: 512 blocks, 4 waves all sharing the 64-kv tile (waves split 128 q rows),
//      complementary pairing -> short block exits early -> 1 wave/SIMD (12.5%
//      occupancy) for most of the kernel; per-tile chain fully latency-exposed.
// New: 1024 blocks of 64 q rows each; the 4 waves split work as
//      (2 q-subtiles) x (2 KV-halves of the staged 64-kv tile).  Each wave runs
//      an independent online softmax over its KV half (defer-max makes this
//      free), merged at the end by an intra-block flash combine through LDS.
//      1024 blocks > 512 resident slots -> hardware backfill; big strips
//      launched first.  2 blocks/CU x 4 waves = 2 waves/SIMD steady-state.
// Per-wave inner math identical to previous version, halved per iteration
// (sacc 1x f32x16, 8 QK MFMA, 16 exp2, 8 PV MFMA).
// Dynamic LDS (65536 B): K0 16K | K1 16K | V0 16K | V1 16K
// ---------------------------------------------------------------------------
__device__ inline void stage_tile(const short* __restrict__ Kp,
                                  const short* __restrict__ Vp,
                                  char* smem, int buf)
{
    short* kls = (short*)(smem + (buf << 14));
    short* vls = (short*)(smem + 32768 + (buf << 14));
    const int tid = threadIdx.x;
#pragma unroll
    for (int i = 0; i < 4; ++i) {
        int c = i * 256 + tid;                  // 0..1023, 16B chunk index
        int lin = c * 16;                       // linear byte in 16 KB tile
        // K tile: 64 rows x 256 B, 16-slot swizzle
        int rk = lin >> 8;
        int kof = ((lin & 255) ^ ((rk & 15) << 4)) >> 1;
        __builtin_amdgcn_global_load_lds(
            (const AS1 void*)(Kp + (size_t)rk * 128 + kof),
            (AS3 void*)(kls + c * 8), 16, 0, 0);
        // V tile: 64 pair-rows x 256 B (r holds d=2r lo-half, d=2r+1 hi-half)
        int rv = lin >> 8;
        int p = (lin & 255) ^ ((rv & 15) << 4);
        int d = rv * 2 + (p >> 7);
        int t = (p & 127) >> 1;
        __builtin_amdgcn_global_load_lds(
            (const AS1 void*)(Vp + (size_t)d * 2048 + t),
            (AS3 void*)(vls + c * 8), 16, 0, 0);
    }
}

__global__ __launch_bounds__(256, 2)
void attn_kernel(const short* __restrict__ qkv, float* __restrict__ out)
{
    extern __shared__ char smem[];
    const int tid = threadIdx.x, lane = tid & 63, wave = tid >> 6;
    const int l31 = lane & 31;
    const int hh_ = lane >> 5;

    // 1024 blocks: bh cycles fastest (round-robin XCD dispatch then keeps
    // ~4 distinct bh per XCD -> KV working set ~4 MB ~= L2); strips big-first
    // so the 32-iteration critical-path blocks start at t=0 and short blocks
    // backfill.
    const int bh = blockIdx.x & 31;
    const int s = 31 - (blockIdx.x >> 5);       // 64-row q strip, 31..0
    const int q0 = s * 64;

    const int qw = wave & 1;                    // q sub-block (32 rows)
    const int kvh = wave >> 1;                  // kv half of staged 64-kv tile
    const int kvoff = kvh * 32;

    const size_t HSTRIDE = (size_t)2048 * 128;
    const short* Kp = qkv + (size_t)bh * HSTRIDE;
    const short* Qp = qkv + (size_t)32 * HSTRIDE + (size_t)bh * HSTRIDE;
    const short* Vp = qkv + (size_t)64 * HSTRIDE + (size_t)bh * 128 * 2048;

    // Q B-operand frags: lane holds Q[q0+qw*32+l31][dblk*16 + hh_*8 + j]
    bf16x8 qf[8];
    {
        const short* qrow = Qp + (size_t)(q0 + qw * 32 + l31) * 128 + hh_ * 8;
#pragma unroll
        for (int dblk = 0; dblk < 8; ++dblk)
            qf[dblk] = *(const bf16x8*)(qrow + dblk * 16);
    }

    // per-lane softmax state for q = l31 (dup across halves), exp2 domain
    float mrow = -1e30f, lrow = 0.f;
    f32x16 acco[4] = {};                        // O[q(reg)][dt*32 + l31]

    const int ntiles = s + 1;
    const int qwave = q0 + qw * 32;
    const int qglob = qwave + l31;

    stage_tile(Kp, Vp, smem, 0);                // prologue: tile 0 -> buf 0
    int cur = 0;

    for (int jt = 0; jt < ntiles; ++jt) {
        const int j0 = jt * 64;
        __builtin_amdgcn_s_barrier();           // all waves done with buf cur^1
        if (jt + 1 < ntiles) {
            stage_tile(Kp + (size_t)(j0 + 64) * 128, Vp + (j0 + 64),
                       smem, cur ^ 1);          // 8 async loads in flight
            asm volatile("s_waitcnt vmcnt(8)" ::: "memory");  // drain buf cur
        } else {
            asm volatile("s_waitcnt vmcnt(0)" ::: "memory");
        }
        __builtin_amdgcn_sched_barrier(0);
        __builtin_amdgcn_s_barrier();           // buf cur visible to all waves
        __builtin_amdgcn_sched_barrier(0);

        const int kv0 = j0 + kvoff;             // this wave's 32-kv start
        // wave-uniform causal gating
        if (kv0 <= qwave + 31) {
            char* Kb = smem + (cur << 14);
            char* Vb = smem + 32768 + (cur << 14);

            // S'^T = K Q'^T : lane pair (l, l^32) holds S'[kv 0..31][q=l31]
            f32x16 sacc = {};
            __builtin_amdgcn_s_setprio(1);
#pragma unroll
            for (int dblk = 0; dblk < 8; ++dblk) {
                int row = kvoff + l31;
                bf16x8 kf = *(const bf16x8*)(Kb + ((row * 256 + dblk * 32 + hh_ * 16) ^ ((row & 15) << 4)));
                sacc = MFMA32(kf, qf[dblk], sacc);
            }
            __builtin_amdgcn_s_setprio(0);

            // causal mask only on the straddle tile
            if (kv0 + 31 > qwave) {
#pragma unroll
                for (int r = 0; r < 16; ++r) {
                    int kvglob = kv0 + (r & 3) + 8 * (r >> 2) + 4 * hh_;
                    if (kvglob > qglob) sacc[r] = -1e30f;
                }
            }

            // row max: in-lane tree + 1 cross-half shuffle
            float pmax = -1e30f;
#pragma unroll
            for (int r = 0; r < 16; r += 4) {
                float a = fmaxf(sacc[r], sacc[r + 1]);
                float b2 = fmaxf(sacc[r + 2], sacc[r + 3]);
                pmax = fmaxf(pmax, fmaxf(a, b2));
            }
            pmax = fmaxf(pmax, __shfl_xor(pmax, 32));

            // defer-max: rescale only when max grew by > 8 nats (11.54 bits)
            if (!__all(pmax - mrow <= 11.5416f)) {
                float mn = fmaxf(mrow, pmax);
                float alpha = __builtin_amdgcn_exp2f(mrow - mn);
                mrow = mn;
                lrow *= alpha;
#pragma unroll
                for (int r = 0; r < 16; ++r) {
                    float ar = __shfl(alpha, (r & 3) + 8 * (r >> 2) + 4 * hh_);
#pragma unroll
                    for (int dt = 0; dt < 4; ++dt) acco[dt][r] *= ar;
                }
            }

            // P = exp2(S' - m'), row sum, pack to bf16 pairs
            float psum = 0.f;
            uint32_t pkA[4], pkB[4];
#pragma unroll
            for (int sg = 0; sg < 4; ++sg) {
                float p0 = __builtin_amdgcn_exp2f(sacc[4 * sg + 0] - mrow);
                float p1 = __builtin_amdgcn_exp2f(sacc[4 * sg + 1] - mrow);
                float p2 = __builtin_amdgcn_exp2f(sacc[4 * sg + 2] - mrow);
                float p3 = __builtin_amdgcn_exp2f(sacc[4 * sg + 3] - mrow);
                psum += (p0 + p1) + (p2 + p3);
                pkA[sg] = pack_bf16(p0, p1);
                pkB[sg] = pack_bf16(p2, p3);
            }
            psum += __shfl_xor(psum, 32);
            lrow += psum;

            // O += P V  (P A-frags assembled in-register via cross-half swaps)
            __builtin_amdgcn_s_setprio(1);
#pragma unroll
            for (int kbl = 0; kbl < 2; ++kbl) {
                uint32_t r0, r1, r2, r3;
                SWAP32(r0, r2, pkA[2 * kbl], pkA[2 * kbl + 1]);
                SWAP32(r1, r3, pkB[2 * kbl], pkB[2 * kbl + 1]);
                union { uint32_t u[4]; bf16x8 v; } pa;
                pa.u[0] = r0; pa.u[1] = r1; pa.u[2] = r2; pa.u[3] = r3;
                const int kb = kvh * 2 + kbl;   // 16-kv slot within 64-kv tile
#pragma unroll
                for (int dt = 0; dt < 4; ++dt) {
                    int d = dt * 32 + l31;
                    int r = d >> 1;
                    int inner = ((d & 1) << 7) + kb * 32 + hh_ * 16;
                    bf16x8 vf = *(const bf16x8*)(Vb + (r * 256 + (inner ^ ((r & 15) << 4))));
                    acco[dt] = MFMA32(pa.v, vf, acco[dt]);
                }
            }
            __builtin_amdgcn_s_setprio(0);
        }

        cur ^= 1;
    }

    // ---- intra-block flash combine: merge KV halves (waves w and w+2) -----
    __syncthreads();                            // all waves done reading LDS
    float* ex = (float*)smem;                   // 2 waves x 4096 f32 (32 KB)
    float* ml = (float*)(smem + 32768);         // 2 waves x 64 x {m,l}
    if (kvh == 1) {
        float* dst = ex + qw * 4096;
#pragma unroll
        for (int dt = 0; dt < 4; ++dt)
#pragma unroll
            for (int r = 0; r < 16; ++r)
                dst[(dt * 16 + r) * 64 + lane] = acco[dt][r];
        ml[qw * 128 + lane * 2 + 0] = mrow;
        ml[qw * 128 + lane * 2 + 1] = lrow;
    }
    __syncthreads();
    if (kvh == 0) {
        float m1 = ml[qw * 128 + lane * 2 + 0];
        float l1 = ml[qw * 128 + lane * 2 + 1];
        float M  = fmaxf(mrow, m1);
        float a  = __builtin_amdgcn_exp2f(mrow - M);
        float b2 = __builtin_amdgcn_exp2f(m1 - M);   // 0 if half fully gated
        float lf = lrow * a + l1 * b2;
        float sA = a / lf, sB = b2 / lf;
        const float* src = ex + qw * 4096;
        const int b = bh >> 3, hd = bh & 7;
#pragma unroll
        for (int r = 0; r < 16; ++r) {
            int ql = (r & 3) + 8 * (r >> 2) + 4 * hh_;
            float sa = __shfl(sA, ql);
            float sb = __shfl(sB, ql);
            int t = qwave + ql;
            float* o = out + (size_t)(b * 2048 + t) * 1024 + hd * 128 + l31;
#pragma unroll
            for (int dt = 0; dt < 4; ++dt)
                o[dt * 32] = acco[dt][r] * sa + src[(dt * 16 + r) * 64 + lane] * sb;
        }
    }
}

// ---------------------------------------------------------------------------
extern "C" void kernel_launch(void* const* d_in, const int* in_sizes, int n_in,
                              void* d_out, int out_size, void* d_ws, size_t ws_size,
                              hipStream_t stream) {
    const float* x  = (const float*)d_in[0];
    const float* w  = (const float*)d_in[1];
    const float* bK = (const float*)d_in[2];
    const float* bQ = (const float*)d_in[3];
    const float* bV = (const float*)d_in[4];

    // workspace layout (bytes): xb 8,388,608 | W 3,145,728 | qkv 50,331,648
    short* xb  = (short*)d_ws;
    short* W   = (short*)((char*)d_ws + 8388608);
    short* qkv = (short*)((char*)d_ws + 8388608 + 3145728);
    float* out = (float*)d_out;

    // allow 64 KB dynamic LDS (idempotent; not a stream op, capture-safe)
    hipFuncSetAttribute((const void*)attn_kernel,
                        hipFuncAttributeMaxDynamicSharedMemorySize, 65536);

    prep_kernel<<<2048, 256, 0, stream>>>(x, w, bK, bQ, bV, xb, W);
    proj_gemm<<<64 * 24, 256, 0, stream>>>(xb, W, qkv);
    attn_kernel<<<32 * 32, 256, 65536, stream>>>(qkv, out);
}